// Round 1
// baseline (505.703 us; speedup 1.0000x reference)
//
#include <hip/hip_runtime.h>
#include <hip/hip_bf16.h>

#define HID   512
#define BATCH 64
#define SRC   2048
#define MROWS (BATCH * SRC)

typedef __bf16 bf16x8 __attribute__((ext_vector_type(8)));
typedef __bf16 bf16x4 __attribute__((ext_vector_type(4)));
typedef float  f32x16 __attribute__((ext_vector_type(16)));

__device__ inline float fast_tanh(float x) {
    // tanh(x) = 1 - 2/(e^{2x}+1); e^{2x} = 2^{x*2*log2(e)}
    float e = __builtin_amdgcn_exp2f(x * 2.8853900817779268f);
    return 1.0f - 2.0f * __builtin_amdgcn_rcpf(e + 1.0f);
}

// ---------------- kernel 1: convert W1 (fp32 [512,512] row-major) -> bf16 ----
__global__ void cvt_w1(const float* __restrict__ W1w, __bf16* __restrict__ W1bf) {
    int i = (blockIdx.x * 256 + threadIdx.x) * 4;
    float4 v = *(const float4*)(W1w + i);
    bf16x4 o;
    o[0] = (__bf16)v.x; o[1] = (__bf16)v.y; o[2] = (__bf16)v.z; o[3] = (__bf16)v.w;
    *(bf16x4*)(W1bf + i) = o;
}

// ---------------- kernel 2: bias_comb[b,o] = h[b]·W2[o,:] + W2_b[o] + W1_b[o]
__global__ void prep_bias(const float* __restrict__ h, const float* __restrict__ W2w,
                          const float* __restrict__ W2b, const float* __restrict__ W1b,
                          float* __restrict__ biasc) {
    int b = blockIdx.x;
    int tid = threadIdx.x;
    __shared__ float hh[HID];
    hh[tid]       = h[b * HID + tid];
    hh[tid + 256] = h[b * HID + tid + 256];
    __syncthreads();
    const float4* h4 = (const float4*)hh;
    for (int o = tid; o < HID; o += 256) {
        const float4* w4 = (const float4*)(W2w + (size_t)o * HID);
        float s = 0.f;
        #pragma unroll 8
        for (int k = 0; k < HID / 4; ++k) {
            float4 a = h4[k]; float4 w = w4[k];
            s += a.x * w.x + a.y * w.y + a.z * w.z + a.w * w.w;
        }
        biasc[b * HID + o] = s + W2b[o] + W1b[o];
    }
}

// ---------------- kernel 3: fused GEMM + tanh + V-dot --------------------------
// grid = MROWS/64 blocks, 512 threads (8 waves). Block handles 64 rows x all 512 o.
// Wave w: wm=w>>2 (which 32-row half), wo=w&3 (which 128-o chunk); 4x mfma 32x32x16.
__global__ __launch_bounds__(512, 2) void attn_main(
        const float* __restrict__ enc, const __bf16* __restrict__ W1bf,
        const float* __restrict__ biasc, const float* __restrict__ Vw,
        float* __restrict__ scores) {
    // LDS staged in MFMA fragment order: panel = 1024B, lane's 16B at lane*16.
    __shared__ __bf16 Abuf[2 * 2 * 512];    // [mtile 2][panel 2][512 elems]
    __shared__ __bf16 Bbuf[16 * 2 * 512];   // [otile 16][panel 2][512 elems]
    __shared__ float bias_lds[HID];
    __shared__ float vw_lds[HID];
    __shared__ float sred[2][4][32];        // [wm][wo][row_local]

    const int tid = threadIdx.x;
    const int blockRow = blockIdx.x * 64;
    const int b = blockIdx.x >> 5;          // 32 blocks per batch row (2048/64)

    bias_lds[tid] = biasc[b * HID + tid];
    vw_lds[tid]   = Vw[tid];

    // ---- staging address setup ----
    // A: 64 rows x 32 k fp32 -> 512 thr * 4 floats
    const int am  = tid >> 3;
    const int akk = (tid & 7) * 4;
    const float* gA = enc + (size_t)(blockRow + am) * HID + akk;
    {
    }
    const int apanel = akk >> 4;
    const int ahalf  = (akk >> 3) & 1;
    const int aj0    = akk & 7;
    const int a_w_off = (((am >> 5) * 2 + apanel) * 512) + ((am & 31) + 32 * ahalf) * 8 + aj0;

    // B: 512 o x 32 k bf16 -> 512 thr * 4 chunks of 8 bf16
    int b_w_off[4];
    const __bf16* gB[4];
    #pragma unroll
    for (int i = 0; i < 4; ++i) {
        int c = tid + 512 * i;
        int o = c >> 2, sub = c & 3, p = sub >> 1, hf = sub & 1;
        b_w_off[i] = ((o >> 5) * 2 + p) * 512 + ((o & 31) + 32 * hf) * 8;
        gB[i] = W1bf + (size_t)o * HID + p * 16 + hf * 8;
    }

    const int lane = tid & 63;
    const int wave = tid >> 6;
    const int wm = wave >> 2;
    const int wo = wave & 3;
    const int a_r_off = (wm * 2) * 512 + lane * 8;
    const int b_r_off = (wo * 4) * 2 * 512 + lane * 8;

    f32x16 acc[4];
    #pragma unroll
    for (int t = 0; t < 4; ++t)
        #pragma unroll
        for (int i = 0; i < 16; ++i) acc[t][i] = 0.f;

    for (int kt = 0; kt < 16; ++kt) {
        // global loads first (overlap with previous compute)
        float4 av = *(const float4*)gA; gA += 32;
        bf16x8 bv[4];
        #pragma unroll
        for (int i = 0; i < 4; ++i) { bv[i] = *(const bf16x8*)gB[i]; gB[i] += 32; }
        bf16x4 ab;
        ab[0] = (__bf16)av.x; ab[1] = (__bf16)av.y; ab[2] = (__bf16)av.z; ab[3] = (__bf16)av.w;

        __syncthreads();   // previous iter's LDS reads done
        *(bf16x4*)&Abuf[a_w_off] = ab;
        #pragma unroll
        for (int i = 0; i < 4; ++i) *(bf16x8*)&Bbuf[b_w_off[i]] = bv[i];
        __syncthreads();   // tiles visible

        bf16x8 a0 = *(const bf16x8*)&Abuf[a_r_off];
        bf16x8 a1 = *(const bf16x8*)&Abuf[a_r_off + 512];
        #pragma unroll
        for (int ot = 0; ot < 4; ++ot) {
            bf16x8 b0 = *(const bf16x8*)&Bbuf[b_r_off + ot * 1024];
            bf16x8 b1 = *(const bf16x8*)&Bbuf[b_r_off + ot * 1024 + 512];
            acc[ot] = __builtin_amdgcn_mfma_f32_32x32x16_bf16(a0, b0, acc[ot], 0, 0, 0);
            acc[ot] = __builtin_amdgcn_mfma_f32_32x32x16_bf16(a1, b1, acc[ot], 0, 0, 0);
        }
    }

    // ---- epilogue: tanh + V-dot, reduce over o ----
    // C layout (verified m74/m101): col = lane&31, row = (reg&3)+8*(reg>>2)+4*(lane>>5)
    float partial[16];
    #pragma unroll
    for (int r = 0; r < 16; ++r) partial[r] = 0.f;
    const int col = lane & 31;
    const int hfi = lane >> 5;
    #pragma unroll
    for (int ot = 0; ot < 4; ++ot) {
        int o = wo * 128 + ot * 32 + col;
        float bb = bias_lds[o];
        float vv = vw_lds[o];
        #pragma unroll
        for (int r = 0; r < 16; ++r) {
            float e = fast_tanh(acc[ot][r] + bb);
            partial[r] += e * vv;
        }
    }
    // reduce across the 32 columns (lanes within each 32-half)
    #pragma unroll
    for (int m = 1; m <= 16; m <<= 1)
        #pragma unroll
        for (int r = 0; r < 16; ++r) partial[r] += __shfl_xor(partial[r], m, 64);

    if (col == 0) {
        #pragma unroll
        for (int r = 0; r < 16; ++r) {
            int rl = (r & 3) + 8 * (r >> 2) + 4 * hfi;
            sred[wm][wo][rl] = partial[r];
        }
    }
    __syncthreads();
    if (tid < 64) {
        int wmx = tid >> 5, rl = tid & 31;
        float s = sred[wmx][0][rl] + sred[wmx][1][rl] + sred[wmx][2][rl] + sred[wmx][3][rl];
        scores[blockRow + wmx * 32 + rl] = s;   // V_b omitted: cancels in softmax
    }
}

// ---------------- kernel 4: in-place softmax over S=2048 per batch row --------
__global__ void softmax_k(float* __restrict__ scores) {
    int b = blockIdx.x;
    int tid = threadIdx.x;
    int lane = tid & 63, wv = tid >> 6;
    __shared__ float red[4];
    float* row = scores + (size_t)b * SRC;
    float4 v0 = *(float4*)(row + tid * 8);
    float4 v1 = *(float4*)(row + tid * 8 + 4);
    float x[8] = {v0.x, v0.y, v0.z, v0.w, v1.x, v1.y, v1.z, v1.w};
    float mx = x[0];
    #pragma unroll
    for (int r = 1; r < 8; ++r) mx = fmaxf(mx, x[r]);
    #pragma unroll
    for (int m = 1; m <= 32; m <<= 1) mx = fmaxf(mx, __shfl_xor(mx, m, 64));
    if (lane == 0) red[wv] = mx;
    __syncthreads();
    mx = fmaxf(fmaxf(red[0], red[1]), fmaxf(red[2], red[3]));
    __syncthreads();
    float s = 0.f;
    #pragma unroll
    for (int r = 0; r < 8; ++r) {
        x[r] = __builtin_amdgcn_exp2f((x[r] - mx) * 1.44269504088896f);
        s += x[r];
    }
    #pragma unroll
    for (int m = 1; m <= 32; m <<= 1) s += __shfl_xor(s, m, 64);
    if (lane == 0) red[wv] = s;
    __syncthreads();
    s = red[0] + red[1] + red[2] + red[3];
    float inv = 1.0f / s;
    float4 o0 = make_float4(x[0] * inv, x[1] * inv, x[2] * inv, x[3] * inv);
    float4 o1 = make_float4(x[4] * inv, x[5] * inv, x[6] * inv, x[7] * inv);
    *(float4*)(row + tid * 8)     = o0;
    *(float4*)(row + tid * 8 + 4) = o1;
}

extern "C" void kernel_launch(void* const* d_in, const int* in_sizes, int n_in,
                              void* d_out, int out_size, void* d_ws, size_t ws_size,
                              hipStream_t stream) {
    const float* h    = (const float*)d_in[0];
    const float* enc  = (const float*)d_in[1];
    const float* W1w  = (const float*)d_in[2];
    const float* W1b  = (const float*)d_in[3];
    const float* W2w  = (const float*)d_in[4];
    const float* W2b  = (const float*)d_in[5];
    const float* Vw   = (const float*)d_in[6];
    // d_in[7] = V_b: unused — constant shift cancels in softmax.
    float* out = (float*)d_out;

    __bf16* W1bf = (__bf16*)d_ws;                                   // 512 KB
    float*  biasc = (float*)((char*)d_ws + HID * HID * sizeof(__bf16)); // 128 KB

    cvt_w1   <<<(HID * HID) / (256 * 4), 256, 0, stream>>>(W1w, W1bf);
    prep_bias<<<BATCH, 256, 0, stream>>>(h, W2w, W2b, W1b, biasc);
    attn_main<<<MROWS / 64, 512, 0, stream>>>(enc, W1bf, biasc, Vw, out);
    softmax_k<<<BATCH, 256, 0, stream>>>(out);
}

// Round 2
// 491.458 us; speedup vs baseline: 1.0290x; 1.0290x over previous
//
#include <hip/hip_runtime.h>
#include <hip/hip_bf16.h>

#define HID   512
#define BATCH 64
#define SRC   2048
#define MROWS (BATCH * SRC)

typedef __bf16 bf16x8 __attribute__((ext_vector_type(8)));
typedef __bf16 bf16x4 __attribute__((ext_vector_type(4)));
typedef float  f32x16 __attribute__((ext_vector_type(16)));

#define PANEL 520          // elems per A panel (512 + 8 skew) = 1040 B

__device__ inline float fast_tanh(float x) {
    float e = __builtin_amdgcn_exp2f(x * 2.8853900817779268f);
    return 1.0f - 2.0f * __builtin_amdgcn_rcpf(e + 1.0f);
}

// ---- kernel 1: pack W1 (fp32 [512,512] row-major) -> bf16 fragment order ----
// Bpk[(kt*16 + ot)*64 + lane][8]: lane l holds o=ot*32+(l&31), k=kt*16+(l>>5)*8+j
__global__ void pack_w1(const float* __restrict__ W1w, __bf16* __restrict__ Bpk) {
    int t = blockIdx.x * 256 + threadIdx.x;     // 32768 threads
    int l = t & 63, tile = t >> 6;
    int ot = tile & 15, kt = tile >> 4;
    int o = ot * 32 + (l & 31);
    int k = kt * 16 + (l >> 5) * 8;
    const float* src = W1w + (size_t)o * HID + k;
    float4 v0 = *(const float4*)src;
    float4 v1 = *(const float4*)(src + 4);
    bf16x8 r;
    r[0]=(__bf16)v0.x; r[1]=(__bf16)v0.y; r[2]=(__bf16)v0.z; r[3]=(__bf16)v0.w;
    r[4]=(__bf16)v1.x; r[5]=(__bf16)v1.y; r[6]=(__bf16)v1.z; r[7]=(__bf16)v1.w;
    ((bf16x8*)Bpk)[t] = r;
}

// ---- kernel 2: bias_comb[b,o] = h[b]·W2[o,:] + W2_b[o] + W1_b[o] ----
__global__ void prep_bias(const float* __restrict__ h, const float* __restrict__ W2w,
                          const float* __restrict__ W2b, const float* __restrict__ W1b,
                          float* __restrict__ biasc) {
    int b = blockIdx.x;
    int tid = threadIdx.x;
    __shared__ float hh[HID];
    hh[tid]       = h[b * HID + tid];
    hh[tid + 256] = h[b * HID + tid + 256];
    __syncthreads();
    const float4* h4 = (const float4*)hh;
    for (int o = tid; o < HID; o += 256) {
        const float4* w4 = (const float4*)(W2w + (size_t)o * HID);
        float s = 0.f;
        #pragma unroll 8
        for (int k = 0; k < HID / 4; ++k) {
            float4 a = h4[k]; float4 w = w4[k];
            s += a.x * w.x + a.y * w.y + a.z * w.z + a.w * w.w;
        }
        biasc[b * HID + o] = s + W2b[o] + W1b[o];
    }
}

// ---- kernel 3: fused GEMM + tanh + V-dot. Barrier-free K-loop. ----
// 2048 blocks x 512 thr. Block: 64 rows x all 512 o. Wave w: otiles {2w,2w+1},
// both 32-row m-tiles. A staged once in LDS (frag order, skewed); B from packed global.
__global__ __launch_bounds__(512, 4) void attn_main(
        const float* __restrict__ enc, const __bf16* __restrict__ Bpk,
        const float* __restrict__ biasc, const float* __restrict__ Vw,
        float* __restrict__ scores) {
    __shared__ __bf16 AL[64 * PANEL];     // 64 panels x 1040 B = 66560 B
    __shared__ float sred[64][9];

    const int tid = threadIdx.x;
    const int blockRow = blockIdx.x * 64;
    const int b = blockIdx.x >> 5;
    const int lane = tid & 63;
    const int wv = tid >> 6;
    const int col = lane & 31;
    const int hfi = lane >> 5;

    // epilogue constants (independent loads, issue early)
    const int o0 = (2 * wv) * 32 + col;
    const int o1 = o0 + 32;
    float bb0 = biasc[b * HID + o0], bb1 = biasc[b * HID + o1];
    float vv0 = Vw[o0],               vv1 = Vw[o1];

    // ---- stage A: 64 rows x 512 k fp32 -> bf16 fragment order ----
    const float4* encB = (const float4*)enc + (size_t)blockRow * 128;
    #pragma unroll
    for (int i = 0; i < 16; ++i) {
        int f = i * 512 + tid;           // coalesced 1KB/wave
        float4 v = encB[f];
        int row = f >> 7;
        int kq  = (f & 127) << 2;        // k of first elem (mult of 4)
        int kt = kq >> 4, half = (kq >> 3) & 1, j = kq & 7;
        int off = (kt * 2 + (row >> 5)) * PANEL + ((row & 31) + 32 * half) * 8 + j;
        bf16x4 o4;
        o4[0]=(__bf16)v.x; o4[1]=(__bf16)v.y; o4[2]=(__bf16)v.z; o4[3]=(__bf16)v.w;
        *(bf16x4*)&AL[off] = o4;
    }
    __syncthreads();                      // the only barrier before epilogue

    // ---- K-loop: 32 steps of k=16, zero LDS-staging, zero barriers ----
    const bf16x8* pB0 = (const bf16x8*)Bpk + (size_t)(2 * wv) * 64 + lane;
    const bf16x8* pB1 = pB0 + 64;
    const __bf16* pA  = AL + lane * 8;

    f32x16 acc00, acc01, acc10, acc11;
    #pragma unroll
    for (int i = 0; i < 16; ++i) { acc00[i]=0.f; acc01[i]=0.f; acc10[i]=0.f; acc11[i]=0.f; }

    bf16x8 b0 = pB0[0];
    bf16x8 b1 = pB1[0];
    #pragma unroll 4
    for (int kt = 0; kt < 32; ++kt) {
        int nk = (kt < 31) ? (kt + 1) : 31;          // clamped prefetch
        bf16x8 nb0 = pB0[(size_t)nk * 1024];
        bf16x8 nb1 = pB1[(size_t)nk * 1024];
        bf16x8 a0 = *(const bf16x8*)(pA + kt * (2 * PANEL));
        bf16x8 a1 = *(const bf16x8*)(pA + kt * (2 * PANEL) + PANEL);
        acc00 = __builtin_amdgcn_mfma_f32_32x32x16_bf16(a0, b0, acc00, 0, 0, 0);
        acc10 = __builtin_amdgcn_mfma_f32_32x32x16_bf16(a1, b0, acc10, 0, 0, 0);
        acc01 = __builtin_amdgcn_mfma_f32_32x32x16_bf16(a0, b1, acc01, 0, 0, 0);
        acc11 = __builtin_amdgcn_mfma_f32_32x32x16_bf16(a1, b1, acc11, 0, 0, 0);
        b0 = nb0; b1 = nb1;
    }

    // ---- epilogue: tanh + V-dot; reduce over all 512 o ----
    // C layout: col = lane&31, row = (r&3) + 8*(r>>2) + 4*(lane>>5)
    float p0[16], p1[16];
    #pragma unroll
    for (int r = 0; r < 16; ++r) {
        p0[r] = vv0 * fast_tanh(acc00[r] + bb0) + vv1 * fast_tanh(acc01[r] + bb1);
        p1[r] = vv0 * fast_tanh(acc10[r] + bb0) + vv1 * fast_tanh(acc11[r] + bb1);
    }
    #pragma unroll
    for (int m = 1; m <= 16; m <<= 1) {
        #pragma unroll
        for (int r = 0; r < 16; ++r) {
            p0[r] += __shfl_xor(p0[r], m, 64);
            p1[r] += __shfl_xor(p1[r], m, 64);
        }
    }
    if (col == 0) {
        #pragma unroll
        for (int r = 0; r < 16; ++r) {
            int rl = (r & 3) + 8 * (r >> 2) + 4 * hfi;
            sred[rl][wv]      = p0[r];
            sred[32 + rl][wv] = p1[r];
        }
    }
    __syncthreads();
    if (tid < 64) {
        float s = 0.f;
        #pragma unroll
        for (int w = 0; w < 8; ++w) s += sred[tid][w];
        scores[blockRow + tid] = s;       // V_b omitted: cancels in softmax
    }
}

// ---- kernel 4: in-place softmax over S=2048 per batch row ----
__global__ void softmax_k(float* __restrict__ scores) {
    int b = blockIdx.x;
    int tid = threadIdx.x;
    int lane = tid & 63, wv = tid >> 6;
    __shared__ float red[4];
    float* row = scores + (size_t)b * SRC;
    float4 v0 = *(float4*)(row + tid * 8);
    float4 v1 = *(float4*)(row + tid * 8 + 4);
    float x[8] = {v0.x, v0.y, v0.z, v0.w, v1.x, v1.y, v1.z, v1.w};
    float mx = x[0];
    #pragma unroll
    for (int r = 1; r < 8; ++r) mx = fmaxf(mx, x[r]);
    #pragma unroll
    for (int m = 1; m <= 32; m <<= 1) mx = fmaxf(mx, __shfl_xor(mx, m, 64));
    if (lane == 0) red[wv] = mx;
    __syncthreads();
    mx = fmaxf(fmaxf(red[0], red[1]), fmaxf(red[2], red[3]));
    __syncthreads();
    float s = 0.f;
    #pragma unroll
    for (int r = 0; r < 8; ++r) {
        x[r] = __builtin_amdgcn_exp2f((x[r] - mx) * 1.44269504088896f);
        s += x[r];
    }
    #pragma unroll
    for (int m = 1; m <= 32; m <<= 1) s += __shfl_xor(s, m, 64);
    if (lane == 0) red[wv] = s;
    __syncthreads();
    s = red[0] + red[1] + red[2] + red[3];
    float inv = 1.0f / s;
    float4 o0 = make_float4(x[0] * inv, x[1] * inv, x[2] * inv, x[3] * inv);
    float4 o1 = make_float4(x[4] * inv, x[5] * inv, x[6] * inv, x[7] * inv);
    *(float4*)(row + tid * 8)     = o0;
    *(float4*)(row + tid * 8 + 4) = o1;
}

extern "C" void kernel_launch(void* const* d_in, const int* in_sizes, int n_in,
                              void* d_out, int out_size, void* d_ws, size_t ws_size,
                              hipStream_t stream) {
    const float* h    = (const float*)d_in[0];
    const float* enc  = (const float*)d_in[1];
    const float* W1w  = (const float*)d_in[2];
    const float* W1b  = (const float*)d_in[3];
    const float* W2w  = (const float*)d_in[4];
    const float* W2b  = (const float*)d_in[5];
    const float* Vw   = (const float*)d_in[6];
    // d_in[7] = V_b: constant shift cancels in softmax.
    float* out = (float*)d_out;

    __bf16* Bpk  = (__bf16*)d_ws;                                       // 512 KB
    float*  biasc = (float*)((char*)d_ws + HID * HID * sizeof(__bf16)); // 128 KB

    pack_w1  <<<128, 256, 0, stream>>>(W1w, Bpk);
    prep_bias<<<BATCH, 256, 0, stream>>>(h, W2w, W2b, W1b, biasc);
    attn_main<<<MROWS / 64, 512, 0, stream>>>(enc, Bpk, biasc, Vw, out);
    softmax_k<<<BATCH, 256, 0, stream>>>(out);
}

// Round 3
// 443.791 us; speedup vs baseline: 1.1395x; 1.1074x over previous
//
#include <hip/hip_runtime.h>
#include <hip/hip_bf16.h>

#define HID   512
#define BATCH 64
#define SRC   2048
#define MROWS (BATCH * SRC)

typedef __bf16 bf16x8 __attribute__((ext_vector_type(8)));
typedef __bf16 bf16x4 __attribute__((ext_vector_type(4)));
typedef float  f32x16 __attribute__((ext_vector_type(16)));

#define PANEL 520          // elems per A panel (512 + 8 skew) = 1040 B

__device__ inline float fast_tanh(float x) {
    float e = __builtin_amdgcn_exp2f(x * 2.8853900817779268f);
    return 1.0f - 2.0f * __builtin_amdgcn_rcpf(e + 1.0f);
}

template <int CTRL>
__device__ inline float dpp_add(float x) {
    int y = __builtin_amdgcn_update_dpp(0, __builtin_bit_cast(int, x), CTRL, 0xF, 0xF, true);
    return x + __builtin_bit_cast(float, y);
}

// sum over the 32 lanes of each 32-lane half (cols of the MFMA tile)
__device__ inline float reduce32(float x) {
    x = dpp_add<0xB1>(x);    // quad_perm [1,0,3,2]  (xor 1)
    x = dpp_add<0x4E>(x);    // quad_perm [2,3,0,1]  (xor 2)
    x = dpp_add<0x141>(x);   // row_half_mirror      (xor 4 equiv)
    x = dpp_add<0x140>(x);   // row_mirror           (xor 8 equiv)
    int y = __builtin_amdgcn_ds_swizzle(__builtin_bit_cast(int, x), 0x401F); // xor 16
    return x + __builtin_bit_cast(float, y);
}

// ---- kernel 1 (fused prep): blocks 0-127 pack W1 -> bf16 fragment order;
//      blocks 128-191: bias_comb[b,o] = h[b]·W2[o,:] + W2_b[o] + W1_b[o]
__global__ void prep(const float* __restrict__ W1w, __bf16* __restrict__ Bpk,
                     const float* __restrict__ h, const float* __restrict__ W2w,
                     const float* __restrict__ W2b, const float* __restrict__ W1b,
                     float* __restrict__ biasc) {
    __shared__ float hh[HID];
    int tid = threadIdx.x;
    if (blockIdx.x < 128) {
        // Bpk[(kt*16 + ot)*64 + lane][8]: lane l holds o=ot*32+(l&31), k=kt*16+(l>>5)*8+j
        int t = blockIdx.x * 256 + tid;
        int l = t & 63, tile = t >> 6;
        int ot = tile & 15, kt = tile >> 4;
        int o = ot * 32 + (l & 31);
        int k = kt * 16 + (l >> 5) * 8;
        const float* src = W1w + (size_t)o * HID + k;
        float4 v0 = *(const float4*)src;
        float4 v1 = *(const float4*)(src + 4);
        bf16x8 r;
        r[0]=(__bf16)v0.x; r[1]=(__bf16)v0.y; r[2]=(__bf16)v0.z; r[3]=(__bf16)v0.w;
        r[4]=(__bf16)v1.x; r[5]=(__bf16)v1.y; r[6]=(__bf16)v1.z; r[7]=(__bf16)v1.w;
        ((bf16x8*)Bpk)[t] = r;
    } else {
        int b = blockIdx.x - 128;
        hh[tid]       = h[b * HID + tid];
        hh[tid + 256] = h[b * HID + tid + 256];
        __syncthreads();
        const float4* h4 = (const float4*)hh;
        for (int o = tid; o < HID; o += 256) {
            const float4* w4 = (const float4*)(W2w + (size_t)o * HID);
            float s = 0.f;
            #pragma unroll 8
            for (int k = 0; k < HID / 4; ++k) {
                float4 a = h4[k]; float4 w = w4[k];
                s += a.x * w.x + a.y * w.y + a.z * w.z + a.w * w.w;
            }
            biasc[b * HID + o] = s + W2b[o] + W1b[o];
        }
    }
}

// ---- kernel 2: fused GEMM + tanh + V-dot. Barrier-free, K-rotated. ----
__global__ __launch_bounds__(512, 4) void attn_main(
        const float* __restrict__ enc, const __bf16* __restrict__ Bpk,
        const float* __restrict__ biasc, const float* __restrict__ Vw,
        float* __restrict__ scores) {
    __shared__ __bf16 AL[64 * PANEL];     // 64 panels x 1040 B = 66560 B
    __shared__ float sred[64][9];

    const int tid = threadIdx.x;
    const int blockRow = blockIdx.x * 64;
    const int b = blockIdx.x >> 5;
    const int lane = tid & 63;
    const int wv = tid >> 6;
    const int col = lane & 31;
    const int hfi = lane >> 5;

    // epilogue constants (issue early)
    const int o0 = (2 * wv) * 32 + col;
    const int o1 = o0 + 32;
    float bb0 = biasc[b * HID + o0], bb1 = biasc[b * HID + o1];
    float vv0 = Vw[o0],               vv1 = Vw[o1];

    // ---- stage A: 64 rows x 512 k fp32 -> bf16 fragment order in LDS ----
    const float4* encB = (const float4*)enc + (size_t)blockRow * 128;
    #pragma unroll
    for (int i = 0; i < 16; ++i) {
        int f = i * 512 + tid;           // coalesced 1KB/wave
        float4 v = encB[f];
        int row = f >> 7;
        int kq  = (f & 127) << 2;
        int kt = kq >> 4, half = (kq >> 3) & 1, j = kq & 7;
        int off = (kt * 2 + (row >> 5)) * PANEL + ((row & 31) + 32 * half) * 8 + j;
        bf16x4 o4;
        o4[0]=(__bf16)v.x; o4[1]=(__bf16)v.y; o4[2]=(__bf16)v.z; o4[3]=(__bf16)v.w;
        *(bf16x4*)&AL[off] = o4;
    }
    __syncthreads();                      // only barrier before epilogue

    // ---- K-loop: 32 steps of k=16, rotated start to spread L2 traffic ----
    const int rot = blockIdx.x & 31;
    const char* BpkB = (const char*)Bpk + (2 * wv) * 1024 + lane * 16;
    const __bf16* pA = AL + lane * 8;

    f32x16 acc00, acc01, acc10, acc11;
    #pragma unroll
    for (int i = 0; i < 16; ++i) { acc00[i]=0.f; acc01[i]=0.f; acc10[i]=0.f; acc11[i]=0.f; }

    bf16x8 b0 = *(const bf16x8*)(BpkB + (size_t)rot * 16384);
    bf16x8 b1 = *(const bf16x8*)(BpkB + (size_t)rot * 16384 + 1024);
    #pragma unroll 8
    for (int kt = 0; kt < 32; ++kt) {
        int in = (kt + 1 + rot) & 31;    // prefetch next (kt=31 wraps: dummy, valid mem)
        bf16x8 nb0 = *(const bf16x8*)(BpkB + (size_t)in * 16384);
        bf16x8 nb1 = *(const bf16x8*)(BpkB + (size_t)in * 16384 + 1024);
        int ia = (kt + rot) & 31;
        const __bf16* pa = pA + ia * (2 * PANEL);
        bf16x8 a0 = *(const bf16x8*)pa;
        bf16x8 a1 = *(const bf16x8*)(pa + PANEL);
        acc00 = __builtin_amdgcn_mfma_f32_32x32x16_bf16(a0, b0, acc00, 0, 0, 0);
        acc10 = __builtin_amdgcn_mfma_f32_32x32x16_bf16(a1, b0, acc10, 0, 0, 0);
        acc01 = __builtin_amdgcn_mfma_f32_32x32x16_bf16(a0, b1, acc01, 0, 0, 0);
        acc11 = __builtin_amdgcn_mfma_f32_32x32x16_bf16(a1, b1, acc11, 0, 0, 0);
        b0 = nb0; b1 = nb1;
    }

    // ---- epilogue: tanh + V-dot; DPP-based 32-lane reduction ----
    // C layout: col = lane&31, row = (r&3) + 8*(r>>2) + 4*(lane>>5)
    #pragma unroll
    for (int r = 0; r < 16; ++r) {
        float p0 = vv0 * fast_tanh(acc00[r] + bb0) + vv1 * fast_tanh(acc01[r] + bb1);
        float p1 = vv0 * fast_tanh(acc10[r] + bb0) + vv1 * fast_tanh(acc11[r] + bb1);
        p0 = reduce32(p0);
        p1 = reduce32(p1);
        if (col == 0) {
            int rl = (r & 3) + 8 * (r >> 2) + 4 * hfi;
            sred[rl][wv]      = p0;
            sred[32 + rl][wv] = p1;
        }
    }
    __syncthreads();
    if (tid < 64) {
        float s = 0.f;
        #pragma unroll
        for (int w = 0; w < 8; ++w) s += sred[tid][w];
        scores[blockRow + tid] = s;       // V_b omitted: cancels in softmax
    }
}

// ---- kernel 3: in-place softmax over S=2048 per batch row ----
__global__ void softmax_k(float* __restrict__ scores) {
    int b = blockIdx.x;
    int tid = threadIdx.x;
    int lane = tid & 63, wv = tid >> 6;
    __shared__ float red[4];
    float* row = scores + (size_t)b * SRC;
    float4 v0 = *(float4*)(row + tid * 8);
    float4 v1 = *(float4*)(row + tid * 8 + 4);
    float x[8] = {v0.x, v0.y, v0.z, v0.w, v1.x, v1.y, v1.z, v1.w};
    float mx = x[0];
    #pragma unroll
    for (int r = 1; r < 8; ++r) mx = fmaxf(mx, x[r]);
    #pragma unroll
    for (int m = 1; m <= 32; m <<= 1) mx = fmaxf(mx, __shfl_xor(mx, m, 64));
    if (lane == 0) red[wv] = mx;
    __syncthreads();
    mx = fmaxf(fmaxf(red[0], red[1]), fmaxf(red[2], red[3]));
    __syncthreads();
    float s = 0.f;
    #pragma unroll
    for (int r = 0; r < 8; ++r) {
        x[r] = __builtin_amdgcn_exp2f((x[r] - mx) * 1.44269504088896f);
        s += x[r];
    }
    #pragma unroll
    for (int m = 1; m <= 32; m <<= 1) s += __shfl_xor(s, m, 64);
    if (lane == 0) red[wv] = s;
    __syncthreads();
    s = red[0] + red[1] + red[2] + red[3];
    float inv = 1.0f / s;
    float4 o0 = make_float4(x[0] * inv, x[1] * inv, x[2] * inv, x[3] * inv);
    float4 o1 = make_float4(x[4] * inv, x[5] * inv, x[6] * inv, x[7] * inv);
    *(float4*)(row + tid * 8)     = o0;
    *(float4*)(row + tid * 8 + 4) = o1;
}

extern "C" void kernel_launch(void* const* d_in, const int* in_sizes, int n_in,
                              void* d_out, int out_size, void* d_ws, size_t ws_size,
                              hipStream_t stream) {
    const float* h    = (const float*)d_in[0];
    const float* enc  = (const float*)d_in[1];
    const float* W1w  = (const float*)d_in[2];
    const float* W1b  = (const float*)d_in[3];
    const float* W2w  = (const float*)d_in[4];
    const float* W2b  = (const float*)d_in[5];
    const float* Vw   = (const float*)d_in[6];
    // d_in[7] = V_b: constant shift cancels in softmax.
    float* out = (float*)d_out;

    __bf16* Bpk  = (__bf16*)d_ws;                                       // 512 KB
    float*  biasc = (float*)((char*)d_ws + HID * HID * sizeof(__bf16)); // 128 KB

    prep     <<<192, 256, 0, stream>>>(W1w, Bpk, h, W2w, W2b, W1b, biasc);
    attn_main<<<MROWS / 64, 512, 0, stream>>>(enc, Bpk, biasc, Vw, out);
    softmax_k<<<BATCH, 256, 0, stream>>>(out);
}